// Round 7
// baseline (1635.193 us; speedup 1.0000x reference)
//
#include <hip/hip_runtime.h>
#include <stdint.h>

// MultiHeadAttention  B=8, S=2048, D=768  (fp32 in/out; bf16 MFMA compute)
//
// Pipeline:
//   convert : all 9 fp32 inputs -> bf16 in ws
//   qkv_k   : fused Q/K/V projections (grid 128x18); V stored transposed Vt[b][e][s]
//   score_k : E = exp(min(Q.K^T/sqrt(D),30)) bf16, rowsum fused into store pass -> rl
//   pv_k    : attn = (E @ V) * rcp(rl)
//   out_k   : out = attn@Wp^T + bp  (fp32)
//
// GEMM core: 128x128 tile, BK=32, global_load_lds width=16, 16x16x32 bf16 MFMA,
// R6 bank swizzle (slot(row,q) = row*4 + ((q+(row>>1))&3); conflicts 7.6e6->4.9e5).
// *** R7 change: LDS diet for occupancy. *** R6 counters: conflicts fixed but
// MfmaUtil stuck ~30% with OccupancyPercent 33% (LDS 34816 B caps 4 blocks/CU,
// achieves ~2.6). All epilogues restructured into half/quarter-tile passes that
// fit 18432 B total (= BK=32 staging 16 KiB + pad) -> 8 blocks/CU LDS ceiling;
// more co-resident waves absorb the barrier vmcnt drain (m114).

typedef __attribute__((ext_vector_type(8))) short short8;
typedef __attribute__((ext_vector_type(4))) float f32x4;

typedef const __attribute__((address_space(1))) void gvoid_t;
typedef __attribute__((address_space(3))) void lvoid_t;

__device__ __forceinline__ float b2f(unsigned short u) {
  union { unsigned int u; float f; } v;
  v.u = ((unsigned int)u) << 16;
  return v.f;
}
__device__ __forceinline__ unsigned short f2b(float f) {
  union { float f; unsigned int u; } v; v.f = f;
  unsigned int u = v.u;
  return (unsigned short)((u + 0x7fffu + ((u >> 16) & 1u)) >> 16);
}

// ---------------- fp32 -> bf16 conversion ----------------
struct Cvt9 {
  const void* s[9];
  unsigned short* d[9];
  long long n8[9];
  long long total8;
};

__global__ __launch_bounds__(256) void convert_inputs(Cvt9 C) {
  long long g = (long long)blockIdx.x * 256 + threadIdx.x;
  if (g >= C.total8) return;
  int s = 0;
  long long off = g;
  while (off >= C.n8[s]) { off -= C.n8[s]; ++s; }
  const float* sf = (const float*)C.s[s] + off * 8;
  unsigned short* dp = C.d[s] + off * 8;
  float4 a = ((const float4*)sf)[0];
  float4 b = ((const float4*)sf)[1];
  uint4 o;
  o.x = (unsigned int)f2b(a.x) | ((unsigned int)f2b(a.y) << 16);
  o.y = (unsigned int)f2b(a.z) | ((unsigned int)f2b(a.w) << 16);
  o.z = (unsigned int)f2b(b.x) | ((unsigned int)f2b(b.y) << 16);
  o.w = (unsigned int)f2b(b.z) | ((unsigned int)f2b(b.w) << 16);
  *(uint4*)dp = o;
}

// ---------------- GEMM core (NT, BK=32, bank-swizzled LDS) ----------------
// LDS per matrix: 4096 elems = [2 rblocks][64 rows][32 k]; 16B-slot(row,q)=row*4+((q+(row>>1))&3)
__device__ __forceinline__ void gemm_core(
    const unsigned short* __restrict__ Ab, const unsigned short* __restrict__ Bb,
    int lda, int ldb, int K, int m0, int n0,
    unsigned short* As, unsigned short* Bs, f32x4 (&acc)[4][4])
{
  const int t    = threadIdx.x;
  const int w    = t >> 6;
  const int lane = t & 63;
  const int lo   = lane & 15;
  const int quad = lane >> 4;
  const int wr   = w >> 1;
  const int wc   = w & 1;
  const int srow  = t >> 2;                              // staging row 0..63
  const int sq    = ((t & 3) - ((t >> 3) & 3)) & 3;      // swizzled source k-slot
  const int skoff = sq * 8;
  const int rq    = ((quad + (lo >> 1)) & 3) * 8;        // swizzled read k-offset (elems)

  for (int k0 = 0; k0 < K; k0 += 32) {
#pragma unroll
    for (int r = 0; r < 2; ++r) {
      const unsigned short* ga = Ab + (size_t)(m0 + r * 64 + srow) * lda + (k0 + skoff);
      __builtin_amdgcn_global_load_lds((gvoid_t*)ga, (lvoid_t*)(As + r * 2048 + w * 512), 16, 0, 0);
      const unsigned short* gb = Bb + (size_t)(n0 + r * 64 + srow) * ldb + (k0 + skoff);
      __builtin_amdgcn_global_load_lds((gvoid_t*)gb, (lvoid_t*)(Bs + r * 2048 + w * 512), 16, 0, 0);
    }
    __syncthreads();

    short8 af[4], bf[4];
#pragma unroll
    for (int i = 0; i < 4; ++i)
      af[i] = *(const short8*)(As + wr * 2048 + (i * 16 + lo) * 32 + rq);
#pragma unroll
    for (int j = 0; j < 4; ++j)
      bf[j] = *(const short8*)(Bs + wc * 2048 + (j * 16 + lo) * 32 + rq);

#pragma unroll
    for (int i = 0; i < 4; ++i)
#pragma unroll
      for (int j = 0; j < 4; ++j)
        acc[i][j] = __builtin_amdgcn_mfma_f32_16x16x32_bf16(af[i], bf[j], acc[i][j], 0, 0, 0);
    __syncthreads();
  }
}

// ---------------- bf16 epilogue: two half-tile passes through 128x72 LDS ----------
// mode 0: v += bias[col]; mode 2: v = exp(min(v*scale,30)); mode 3: v *= rcp(rl[row])
// rowsum_g != nullptr: per-row sums of stored values atomicAdd'ed (used by score).
__device__ __forceinline__ void epilogue_bf16(
    unsigned short* Ls, f32x4 (&acc)[4][4], int mode,
    const unsigned short* bias_n0, const float* rlrow, float scale,
    unsigned short* Cg, int ldc, float* rowsum_g)
{
  const int t = threadIdx.x;
  const int w = t >> 6, lane = t & 63;
  const int lo = lane & 15, quad = lane >> 4, wr = w >> 1, wc = w & 1;
  const int sr = t >> 3, sc = (t & 7) * 8;
  float rsum[4] = {0.f, 0.f, 0.f, 0.f};
#pragma unroll
  for (int h = 0; h < 2; ++h) {
    __syncthreads();
    if (wc == h) {
#pragma unroll
      for (int j = 0; j < 4; ++j) {
        const int cl = j * 16 + lo;
        const float bv = (mode == 0) ? b2f(bias_n0[h * 64 + cl]) : 0.f;
#pragma unroll
        for (int i = 0; i < 4; ++i) {
          const int rt = wr * 64 + i * 16 + quad * 4;
#pragma unroll
          for (int r = 0; r < 4; ++r) {
            float v = acc[i][j][r];
            if (mode == 0)      v += bv;
            else if (mode == 2) v = __expf(fminf(v * scale, 30.f));
            else                v *= __builtin_amdgcn_rcpf(rlrow[rt + r]);
            Ls[(rt + r) * 72 + cl] = f2b(v);
          }
        }
      }
    }
    __syncthreads();
#pragma unroll
    for (int it = 0; it < 4; ++it) {
      const int row = it * 32 + sr;
      uint4 v = *(const uint4*)(Ls + row * 72 + sc);
      *(uint4*)(Cg + (size_t)row * ldc + h * 64 + sc) = v;
      if (rowsum_g) {
        unsigned int uu[4] = {v.x, v.y, v.z, v.w};
#pragma unroll
        for (int c = 0; c < 4; ++c)
          rsum[it] += b2f((unsigned short)(uu[c] & 0xffffu)) + b2f((unsigned short)(uu[c] >> 16));
      }
    }
  }
  if (rowsum_g) {
#pragma unroll
    for (int it = 0; it < 4; ++it) {
      float s = rsum[it];
      s += __shfl_xor(s, 1);
      s += __shfl_xor(s, 2);
      s += __shfl_xor(s, 4);
      if ((t & 7) == 0) atomicAdd(rowsum_g + it * 32 + sr, s);
    }
  }
}

// ---------------- qkv: fused projections ----------------
__global__ __launch_bounds__(256, 6) void qkv_k(
    const unsigned short* __restrict__ xb,
    const unsigned short* __restrict__ Wq, const unsigned short* __restrict__ bq,
    const unsigned short* __restrict__ Wk, const unsigned short* __restrict__ bk,
    const unsigned short* __restrict__ Wv, const unsigned short* __restrict__ bv,
    unsigned short* __restrict__ qb, unsigned short* __restrict__ kb,
    unsigned short* __restrict__ vt)
{
  __shared__ unsigned short smem[9216];   // 18432 B
  const int sel = blockIdx.y / 6;
  const int n0  = (blockIdx.y % 6) * 128;
  const int m0  = blockIdx.x * 128;

  const unsigned short* W;
  const unsigned short* bi;
  if (sel == 0)      { W = Wq; bi = bq; }
  else if (sel == 1) { W = Wk; bi = bk; }
  else               { W = Wv; bi = bv; }

  f32x4 acc[4][4] = {};
  gemm_core(xb, W, 768, 768, 768, m0, n0, smem, smem + 4096, acc);

  const int t = threadIdx.x;
  const int w = t >> 6, lane = t & 63;
  const int lo = lane & 15, quad = lane >> 4, wr = w >> 1, wc = w & 1;

  if (sel < 2) {
    unsigned short* dst = (sel == 0) ? qb : kb;
    epilogue_bf16(smem, acc, 0, bi + n0, nullptr, 0.f,
                  dst + (size_t)m0 * 768 + n0, 768, nullptr);
    return;
  }

  // V: transpose epilogue into Vt[b][e][s], two passes of 64 e-cols ([64][136] LDS)
  const int bb  = m0 >> 11;
  const int sin = m0 & 2047;
  unsigned short* Cb = vt + (size_t)bb * (768 * 2048) + (size_t)n0 * 2048 + sin;
  unsigned short* Ls = smem;
  const int er = t >> 4, sc = (t & 15) * 8;
#pragma unroll
  for (int h = 0; h < 2; ++h) {
    __syncthreads();
    if (wc == h) {
#pragma unroll
      for (int j = 0; j < 4; ++j) {
        const int cl = j * 16 + lo;           // local e-col 0..63
        const float bvv = b2f(bi[n0 + h * 64 + cl]);
#pragma unroll
        for (int i = 0; i < 4; ++i) {
          const int rt = wr * 64 + i * 16 + quad * 4;
          ushort4 pk;
          pk.x = f2b(acc[i][j][0] + bvv);
          pk.y = f2b(acc[i][j][1] + bvv);
          pk.z = f2b(acc[i][j][2] + bvv);
          pk.w = f2b(acc[i][j][3] + bvv);
          *(ushort4*)(Ls + cl * 136 + rt) = pk;
        }
      }
    }
    __syncthreads();
#pragma unroll
    for (int it = 0; it < 4; ++it) {
      const int e = it * 16 + er;
      uint4 v = *(const uint4*)(Ls + e * 136 + sc);
      *(uint4*)(Cb + (size_t)(h * 64 + e) * 2048 + sc) = v;
    }
  }
}

// ---------------- score: E = exp(QK^T/sqrt(D)) + fused rowsum ----------------
__global__ __launch_bounds__(256, 6) void score_k(
    const unsigned short* __restrict__ Q, const unsigned short* __restrict__ Kb,
    unsigned short* __restrict__ E, float* __restrict__ rl, float scale)
{
  __shared__ unsigned short smem[9216];
  const int m0 = blockIdx.x * 128, n0 = blockIdx.y * 128, bz = blockIdx.z;

  f32x4 acc[4][4] = {};
  gemm_core(Q + (size_t)bz * 1572864, Kb + (size_t)bz * 1572864,
            768, 768, 768, m0, n0, smem, smem + 4096, acc);

  epilogue_bf16(smem, acc, 2, nullptr, nullptr, scale,
                E + (size_t)bz * 4194304 + (size_t)m0 * 2048 + n0, 2048,
                rl + bz * 2048 + m0);
}

// ---------------- pv: attn = (E @ V) * rcp(rowsum) ----------------
__global__ __launch_bounds__(256, 6) void pv_k(
    const unsigned short* __restrict__ E, const unsigned short* __restrict__ Vt,
    const float* __restrict__ rl, unsigned short* __restrict__ attn)
{
  __shared__ unsigned short smem[9216];
  const int m0 = blockIdx.x * 128, n0 = blockIdx.y * 128, bz = blockIdx.z;

  f32x4 acc[4][4] = {};
  gemm_core(E + (size_t)bz * 4194304, Vt + (size_t)bz * 1572864,
            2048, 2048, 2048, m0, n0, smem, smem + 4096, acc);

  epilogue_bf16(smem, acc, 3, nullptr, rl + bz * 2048 + m0, 0.f,
                attn + (size_t)bz * 1572864 + (size_t)m0 * 768 + n0, 768, nullptr);
}

// ---------------- out: final projection (fp32), four quarter-tile passes ----------
__global__ __launch_bounds__(256, 6) void out_k(
    const unsigned short* __restrict__ attn,
    const unsigned short* __restrict__ Wp, const unsigned short* __restrict__ bp,
    float* __restrict__ Of)
{
  __shared__ unsigned short smem[9216];
  const int m0 = blockIdx.x * 128, n0 = blockIdx.y * 128;

  f32x4 acc[4][4] = {};
  gemm_core(attn, Wp, 768, 768, 768, m0, n0, smem, smem + 4096, acc);

  const int t = threadIdx.x;
  const int w = t >> 6, lane = t & 63;
  const int lo = lane & 15, quad = lane >> 4, wr = w >> 1, wc = w & 1;
  float* Lf = (float*)smem;               // [128][36] floats = 18432 B
  const int sr = t >> 3, c4 = (t & 7) * 4;
#pragma unroll
  for (int h = 0; h < 4; ++h) {           // cols [32h, 32h+32)
    __syncthreads();
    if (wc == (h >> 1)) {
#pragma unroll
      for (int jj = 0; jj < 2; ++jj) {
        const int j = (h & 1) * 2 + jj;
        const int cl = jj * 16 + lo;      // 0..31
        const float bvv = b2f(bp[n0 + h * 32 + cl]);
#pragma unroll
        for (int i = 0; i < 4; ++i) {
          const int rt = wr * 64 + i * 16 + quad * 4;
#pragma unroll
          for (int r = 0; r < 4; ++r)
            Lf[(rt + r) * 36 + cl] = acc[i][j][r] + bvv;
        }
      }
    }
    __syncthreads();
#pragma unroll
    for (int it = 0; it < 4; ++it) {
      const int row = it * 32 + sr;
      float4 v = *(const float4*)(Lf + row * 36 + c4);
      *(float4*)(Of + (size_t)(m0 + row) * 768 + n0 + h * 32 + c4) = v;
    }
  }
}

extern "C" void kernel_launch(void* const* d_in, const int* in_sizes, int n_in,
                              void* d_out, int out_size, void* d_ws, size_t ws_size,
                              hipStream_t stream) {
  (void)in_sizes; (void)n_in; (void)out_size; (void)ws_size;

  char* ws = (char*)d_ws;
  float* rl    = (float*)(ws + 4096);
  unsigned short* wcv = (unsigned short*)(ws + ((size_t)1 << 20));
  unsigned short* qb  = (unsigned short*)(ws + ((size_t)8  << 20));
  unsigned short* kb  = (unsigned short*)(ws + ((size_t)32 << 20));
  unsigned short* vt  = (unsigned short*)(ws + ((size_t)56 << 20));
  unsigned short* eb  = (unsigned short*)(ws + ((size_t)80 << 20));
  unsigned short* xb  = eb;     // converted x aliases E (x dead before score_k writes E)
  unsigned short* attn = qb;    // Q dead after score_k

  unsigned short* wqb = wcv;
  unsigned short* bqb = wcv + 589824;
  unsigned short* wkb = wcv + 590592;
  unsigned short* bkb = wcv + 1180416;
  unsigned short* wvb = wcv + 1181184;
  unsigned short* bvb = wcv + 1771008;
  unsigned short* wpb = wcv + 1771776;
  unsigned short* bpb = wcv + 2361600;

  const float inv_scale = 0.036084391824351615f;  // 1/sqrt(768)
  dim3 blk(256);

  Cvt9 cv;
  cv.s[0] = d_in[0]; cv.d[0] = xb;  cv.n8[0] = 12582912 / 8;
  cv.s[1] = d_in[1]; cv.d[1] = wqb; cv.n8[1] = 589824 / 8;
  cv.s[2] = d_in[2]; cv.d[2] = bqb; cv.n8[2] = 768 / 8;
  cv.s[3] = d_in[3]; cv.d[3] = wkb; cv.n8[3] = 589824 / 8;
  cv.s[4] = d_in[4]; cv.d[4] = bkb; cv.n8[4] = 768 / 8;
  cv.s[5] = d_in[5]; cv.d[5] = wvb; cv.n8[5] = 589824 / 8;
  cv.s[6] = d_in[6]; cv.d[6] = bvb; cv.n8[6] = 768 / 8;
  cv.s[7] = d_in[7]; cv.d[7] = wpb; cv.n8[7] = 589824 / 8;
  cv.s[8] = d_in[8]; cv.d[8] = bpb; cv.n8[8] = 768 / 8;
  cv.total8 = (12582912 + 4 * (589824 + 768)) / 8;
  convert_inputs<<<(unsigned)((cv.total8 + 255) / 256), blk, 0, stream>>>(cv);

  hipMemsetAsync(rl, 0, 16384 * sizeof(float), stream);

  qkv_k<<<dim3(128, 18, 1), blk, 0, stream>>>(xb, wqb, bqb, wkb, bkb, wvb, bvb, qb, kb, vt);

  score_k<<<dim3(16, 16, 8), blk, 0, stream>>>(qb, kb, eb, rl, inv_scale);

  pv_k<<<dim3(16, 6, 8), blk, 0, stream>>>(eb, vt, rl, attn);

  out_k<<<dim3(128, 6, 1), blk, 0, stream>>>(attn, wpb, bpb, (float*)d_out);
}